// Round 3
// baseline (255.639 us; speedup 1.0000x reference)
//
#include <hip/hip_runtime.h>
#include <stdint.h>

typedef unsigned long long u64;
typedef unsigned int u32;

constexpr int kC  = 256;
constexpr int kHW = 3136;             // 56*56
constexpr int kN  = 32;
constexpr int kP  = kN * kHW;         // 100352 spatial positions
constexpr int kPos = 64;              // positions per pack/finalize block
constexpr int kBlk = kP / kPos;       // 1568  (6.1 blocks/CU, 24 waves/CU)
constexpr int kRedBlk  = 16;          // reduce blocks
constexpr int kRedRows = kBlk / kRedBlk;  // 98

// d_ws layout (bytes):
constexpr size_t OFF_T     = 0;        // u64 [4][256]  packed w-sign planes (plane-major)
constexpr size_t OFF_SCALE = 8192;     // f32 [256]
constexpr size_t OFF_SUMD  = 9216;     // i64 [256]  sum of dot
constexpr size_t OFF_SUMD2 = 11264;    // i64 [256]  sum of dot^2
constexpr size_t OFF_S     = 13312;    // u64 [4][kP] packed x-sign planes (SoA)
constexpr size_t OFF_PS    = 3224576;  // i32 [1568][256] per-block summ partials
constexpr size_t OFF_PQ    = 4830208;  // i32 [1568][256] per-block summ2 partials

struct alignas(16) U64x2 { u64 x, y; };

// ---------------------------------------------------------------------------
// Kernel A: w-prep. 16 blocks x 256. Builds T (w-sign planes) + scale;
// block 0 zeros the stat accumulators. ~2 us, reads 256 KB.
// Must be a separate dispatch: every pack_stats block needs T.
// ---------------------------------------------------------------------------
__global__ __launch_bounds__(256) void prep_kernel(
    const float* __restrict__ w, char* __restrict__ ws) {
  int t = threadIdx.x;
  int b = blockIdx.x;
  u64*   T     = (u64*)(ws + OFF_T);
  float* scale = (float*)(ws + OFF_SCALE);
  int kk = t >> 6, ln = t & 63;
  if (b == 0) {
    ((u64*)(ws + OFF_SUMD))[t]  = 0ull;
    ((u64*)(ws + OFF_SUMD2))[t] = 0ull;
  }
  __shared__ float part[4][16];
#pragma unroll
  for (int i = 0; i < 16; ++i) {
    int o = b * 16 + i;
    float v = w[o * kC + kk * 64 + ln];   // coalesced 256B/wave
    u64 m = __ballot(v >= 0.0f);
    float a = fabsf(v);
#pragma unroll
    for (int s = 32; s > 0; s >>= 1) a += __shfl_xor(a, s, 64);
    if (ln == 0) { T[kk * 256 + o] = m; part[kk][i] = a; }
  }
  __syncthreads();
  if (t < 16) {
    int o = b * 16 + t;
    scale[o] = (part[0][t] + part[1][t] + part[2][t] + part[3][t]) * (1.0f / 256.0f);
  }
}

// ---------------------------------------------------------------------------
// Kernel B: fused sign-pack + stats, at the PROVEN 1568-block geometry
// (R1's 784-block fusion was latency-bound at 3 blocks/CU; 6 blocks/CU here
// gives 5 co-resident blocks to overlap each block's barrier+stats phase).
// Pack: 1 pos/lane, PLAIN x loads (allocate in L3 for finalize's re-read).
// Stats: after barrier, thread=channel popcounts the block's own 64
// positions from L1/L2-hot S; partials written coalesced, no atomics.
// ---------------------------------------------------------------------------
__global__ __launch_bounds__(256) void pack_stats_kernel(
    const float* __restrict__ x, const float* __restrict__ bias0,
    char* __restrict__ ws) {
  int t = threadIdx.x;
  int b = blockIdx.x;
  int k    = __builtin_amdgcn_readfirstlane(t >> 6);  // wave-uniform chunk
  int lane = t & 63;
  u32 pb = (u32)b * (u32)kPos;
  u32 p  = pb + (u32)lane;
  u32 n  = p / kHW;
  u32 hw = p - n * kHW;
  const float* xp = x + (size_t)n * kC * kHW + (size_t)(k * 64) * kHW + hw;
  const float* bp = bias0 + k * 64;                   // uniform -> s_load

  u64 m = 0;
#pragma unroll 32
  for (int i = 0; i < 64; ++i) {
    float v = xp[(size_t)i * kHW] + bp[i];            // plain: seed L3
    m |= (u64)(v >= 0.0f) << i;
  }
  u64* S = (u64*)(ws + OFF_S);
  S[(size_t)k * kP + p] = m;                          // 8B/lane, 512B/wave

  __syncthreads();   // drains vmcnt -> block's S visible to all 4 waves

  const u64* T = (const u64*)(ws + OFF_T);
  u64 t0 = T[t], t1 = T[256 + t], t2 = T[512 + t], t3 = T[768 + t];
  int summ = 0, summ2 = 0;
#pragma unroll 8
  for (int j = 0; j < kPos; j += 2) {
    u32 q = pb + j;                                  // uniform -> broadcast
    U64x2 a0 = *(const U64x2*)&S[q];
    U64x2 a1 = *(const U64x2*)&S[kP + q];
    U64x2 a2 = *(const U64x2*)&S[2 * kP + q];
    U64x2 a3 = *(const U64x2*)&S[3 * kP + q];
    int ka = __popcll(a0.x ^ t0) + __popcll(a1.x ^ t1) +
             __popcll(a2.x ^ t2) + __popcll(a3.x ^ t3);
    int kb = __popcll(a0.y ^ t0) + __popcll(a1.y ^ t1) +
             __popcll(a2.y ^ t2) + __popcll(a3.y ^ t3);
    int ma = 128 - ka, mb = 128 - kb;
    summ  += ma + mb;
    summ2 += ma * ma + mb * mb;
  }
  ((int*)(ws + OFF_PS))[b * 256 + t] = summ;   // coalesced 1 KB/block
  ((int*)(ws + OFF_PQ))[b * 256 + t] = summ2;  // coalesced 1 KB/block
}

// ---------------------------------------------------------------------------
// Kernel C: reduce partials. 16 blocks x 256; thread sums 98 rows of its
// channel column (1 KB/row coalesced, L2-resident), then ONE u64 atomic
// per stat (16 atomics/address total -- proven negligible in R2).
// ---------------------------------------------------------------------------
__global__ __launch_bounds__(256) void reduce_kernel(char* __restrict__ ws) {
  int t = threadIdx.x;
  int b = blockIdx.x;
  const int* PS = (const int*)(ws + OFF_PS);
  const int* PQ = (const int*)(ws + OFF_PQ);
  long long s = 0, q = 0;
#pragma unroll 7
  for (int r = 0; r < kRedRows; ++r) {
    int row = b * kRedRows + r;
    s += PS[row * 256 + t];
    q += PQ[row * 256 + t];
  }
  atomicAdd((u64*)(ws + OFF_SUMD) + t,  (u64)(long long)(2 * s));
  atomicAdd((u64*)(ws + OFF_SUMD2) + t, (u64)(long long)(4 * q));
}

// ---------------------------------------------------------------------------
// Kernel D: BN coefs + fused epilogue (R0 proven structure).
//   u = 2*cA*m + cB + x ;  out = (u>0 ? u : alpha*u) + bias2
// x loads now PLAIN (expected L3-resident: harness restore + pack both
// touched it cached); out stores stay NT (pure drain stream).
// ---------------------------------------------------------------------------
__global__ __launch_bounds__(256) void finalize_kernel(
    const float* __restrict__ x, const float* __restrict__ gamma,
    const float* __restrict__ beta, const float* __restrict__ bias1,
    const float* __restrict__ alpha, const float* __restrict__ bias2,
    const char* __restrict__ ws, float* __restrict__ out) {
  __shared__ u64    ldsT[256][4];   // [o][plane]: broadcast ds_read_b128 x2
  __shared__ float4 ldsC[256];      // {2*cA, cB, alpha, bias2}

  int t = threadIdx.x;
  {
    const u64* T = (const u64*)(ws + OFF_T);
#pragma unroll
    for (int q = 0; q < 4; ++q) ldsT[t][q] = T[q * 256 + t];

    const float*     scale = (const float*)(ws + OFF_SCALE);
    const long long* sumd  = (const long long*)(ws + OFF_SUMD);
    const long long* sumd2 = (const long long*)(ws + OFF_SUMD2);
    double inv  = 1.0 / (double)kP;
    double md   = (double)sumd[t] * inv;
    double e2   = (double)sumd2[t] * inv;
    double vard = e2 - md * md;
    float sc  = scale[t];
    float mu  = sc * (float)md;
    float var = sc * sc * (float)vard;
    float rs  = rsqrtf(var + 1e-5f);
    float g   = gamma[t];
    float cA  = g * rs * sc;
    float cB  = beta[t] - g * rs * mu + bias1[t];
    ldsC[t] = make_float4(2.0f * cA, cB, alpha[t], bias2[t]);
  }
  __syncthreads();

  int k    = __builtin_amdgcn_readfirstlane(t >> 6);
  int lane = t & 63;
  u32 p  = blockIdx.x * (u32)kPos + (u32)lane;
  u32 n  = p / kHW;
  u32 hw = p - n * kHW;

  const u64* S = (const u64*)(ws + OFF_S);
  u64 s0 = S[p];                       // 8B/lane coalesced, L2-hot
  u64 s1 = S[kP + p];
  u64 s2 = S[2 * kP + p];
  u64 s3 = S[3 * kP + p];

  const float* xp = x   + (size_t)n * kC * kHW + (size_t)(k * 64) * kHW + hw;
  float*       op = out + (size_t)n * kC * kHW + (size_t)(k * 64) * kHW + hw;

#pragma unroll 8
  for (int i = 0; i < 64; ++i) {
    int o = k * 64 + i;                // wave-uniform -> LDS broadcast
    u64 w0 = ldsT[o][0], w1 = ldsT[o][1], w2 = ldsT[o][2], w3 = ldsT[o][3];
    int kx = __popcll(s0 ^ w0) + __popcll(s1 ^ w1) +
             __popcll(s2 ^ w2) + __popcll(s3 ^ w3);
    float4 cc = ldsC[o];
    float xv = xp[(size_t)i * kHW];    // plain: L3-hit expected
    float u  = fmaf(cc.x, (float)(128 - kx), cc.y) + xv;
    float r  = u > 0.0f ? u : cc.z * u;
    __builtin_nontemporal_store(r + cc.w, op + (size_t)i * kHW);
  }
}

extern "C" void kernel_launch(void* const* d_in, const int* in_sizes, int n_in,
                              void* d_out, int out_size, void* d_ws, size_t ws_size,
                              hipStream_t stream) {
  const float* x     = (const float*)d_in[0];
  const float* bias0 = (const float*)d_in[1];
  const float* w     = (const float*)d_in[2];
  const float* gamma = (const float*)d_in[3];
  const float* beta  = (const float*)d_in[4];
  const float* bias1 = (const float*)d_in[5];
  const float* alpha = (const float*)d_in[6];
  const float* bias2 = (const float*)d_in[7];
  float* out = (float*)d_out;
  char*  ws  = (char*)d_ws;

  hipLaunchKernelGGL(prep_kernel, dim3(16), dim3(256), 0, stream, w, ws);
  hipLaunchKernelGGL(pack_stats_kernel, dim3(kBlk), dim3(256), 0, stream,
                     x, bias0, ws);
  hipLaunchKernelGGL(reduce_kernel, dim3(kRedBlk), dim3(256), 0, stream, ws);
  hipLaunchKernelGGL(finalize_kernel, dim3(kBlk), dim3(256), 0, stream,
                     x, gamma, beta, bias1, alpha, bias2, ws, out);
}